// Round 2
// baseline (106.408 us; speedup 1.0000x reference)
//
#include <hip/hip_runtime.h>
#include <hip/hip_bf16.h>

// x [16,64,256,256] f32, haar [256,256] f32 -> out [16,64,128,128] f32.
// out[b,c2,i2,j2] = res[b, i2&63, 4*c2+(i2>>6), j2], res = X @ (haar@haar).
// Only x-rows i with i%4 in {0,1} and cols j<128 of res are needed.

typedef __attribute__((ext_vector_type(8))) short bf16x8;
typedef __attribute__((ext_vector_type(4))) float f32x4;

// ---------------------------------------------------------------- H2^T (bf16)
// h2t[n*256 + k] = bf16( sum_t haar[k][t] * haar[t][n] ),  n in [0,128)
__global__ void h2t_kernel(const float* __restrict__ haar,
                           unsigned short* __restrict__ h2t) {
    __shared__ float rowk[256];
    __shared__ float part[128];
    const int k   = blockIdx.x;     // 0..255
    const int tid = threadIdx.x;    // 0..255
    const int n   = tid & 127;
    const int h   = tid >> 7;       // t-half
    rowk[tid] = haar[k * 256 + tid];
    __syncthreads();
    float acc = 0.f;
    const int t0 = h * 128;
#pragma unroll 8
    for (int t = 0; t < 128; ++t)
        acc = fmaf(rowk[t0 + t], haar[(t0 + t) * 256 + n], acc);  // coalesced in n
    if (h) part[n] = acc;
    __syncthreads();
    if (!h) {
        __hip_bfloat16 bv = __float2bfloat16(acc + part[n]);
        h2t[n * 256 + k] = *reinterpret_cast<unsigned short*>(&bv);
    }
}

// ---------------------------------------------------------------- main GEMM
static __device__ inline bf16x8 cvt8(f32x4 a, f32x4 b) {
    union { bf16x8 v; __hip_bfloat16 h[8]; } u;
    u.h[0] = __float2bfloat16(a.x);
    u.h[1] = __float2bfloat16(a.y);
    u.h[2] = __float2bfloat16(a.z);
    u.h[3] = __float2bfloat16(a.w);
    u.h[4] = __float2bfloat16(b.x);
    u.h[5] = __float2bfloat16(b.y);
    u.h[6] = __float2bfloat16(b.z);
    u.h[7] = __float2bfloat16(b.w);
    return u.v;
}

// 2048 blocks: block = (matrix blk, row-half mt). 4 waves in 2x2; each wave a
// 32x64 quadrant as 2x4 fragments of mfma_f32_16x16x32_bf16. Depth-2 pipeline.
__global__ __launch_bounds__(256, 4)
void wavelet_gemm_kernel(const float* __restrict__ x,
                         const unsigned short* __restrict__ h2t,
                         float* __restrict__ out) {
    const int bid  = blockIdx.x;
    const int blk  = bid >> 1;        // b*64 + c
    const int mt   = bid & 1;         // which 64 of the 128 selected rows
    const int c    = blk & 63;
    const int b    = blk >> 6;
    const int tid  = threadIdx.x;
    const int lane = tid & 63;
    const int wid  = tid >> 6;        // 0..3
    const int wr   = wid >> 1;        // 32-row group
    const int wc   = wid & 1;         // 64-col group
    const int lr   = lane & 15;
    const int lg   = lane >> 4;

    const float* xb = x + (size_t)blk * 65536;

    // A/B per-lane base pointers; same k-mapping (lg*8) on both sides so any
    // internal hw k-permutation cancels.
    const f32x4* ap[2];
#pragma unroll
    for (int fa = 0; fa < 2; ++fa) {
        int m = mt * 64 + wr * 32 + fa * 16 + lr;   // selected-row 0..127
        int i = ((m >> 1) << 2) | (m & 1);          // x row (i%4 in {0,1})
        ap[fa] = reinterpret_cast<const f32x4*>(xb + i * 256 + lg * 8);
    }
    const unsigned short* bp[4];
#pragma unroll
    for (int fb = 0; fb < 4; ++fb) {
        int n = wc * 64 + fb * 16 + lr;             // output col 0..127
        bp[fb] = h2t + n * 256 + lg * 8;
    }

    f32x4 acc[2][4] = {};

    // ---- depth-2 software pipeline over 8 k-steps (k0 = it*32) ----
    f32x4 a0[2][2];
    bf16x8 b0[4];
#pragma unroll
    for (int fa = 0; fa < 2; ++fa) {
        a0[fa][0] = __builtin_nontemporal_load(ap[fa]);
        a0[fa][1] = __builtin_nontemporal_load(ap[fa] + 1);
    }
#pragma unroll
    for (int fb = 0; fb < 4; ++fb)
        b0[fb] = *reinterpret_cast<const bf16x8*>(bp[fb]);

#pragma unroll
    for (int it = 0; it < 8; ++it) {
        f32x4 a1[2][2];
        bf16x8 b1[4];
        if (it < 7) {
            const int koff = (it + 1) * 8;          // in f32x4 units: *32/4
#pragma unroll
            for (int fa = 0; fa < 2; ++fa) {
                a1[fa][0] = __builtin_nontemporal_load(ap[fa] + koff);
                a1[fa][1] = __builtin_nontemporal_load(ap[fa] + koff + 1);
            }
#pragma unroll
            for (int fb = 0; fb < 4; ++fb)
                b1[fb] = *reinterpret_cast<const bf16x8*>(bp[fb] + (it + 1) * 32);
        }
        bf16x8 aF[2];
#pragma unroll
        for (int fa = 0; fa < 2; ++fa)
            aF[fa] = cvt8(a0[fa][0], a0[fa][1]);
#pragma unroll
        for (int fa = 0; fa < 2; ++fa)
#pragma unroll
            for (int fb = 0; fb < 4; ++fb)
                acc[fa][fb] = __builtin_amdgcn_mfma_f32_16x16x32_bf16(
                    aF[fa], b0[fb], acc[fa][fb], 0, 0, 0);
        if (it < 7) {
#pragma unroll
            for (int fa = 0; fa < 2; ++fa) {
                a0[fa][0] = a1[fa][0];
                a0[fa][1] = a1[fa][1];
            }
#pragma unroll
            for (int fb = 0; fb < 4; ++fb)
                b0[fb] = b1[fb];
        }
    }

    // Epilogue: C/D layout col=lane&15, row=(lane>>4)*4+r; scatter through the
    // reshape scramble: out[((b*64+(m>>1))*128 + (m&1)*64 + c)*128 + j]
#pragma unroll
    for (int fa = 0; fa < 2; ++fa) {
        const int mbase = mt * 64 + wr * 32 + fa * 16 + lg * 4;
#pragma unroll
        for (int fb = 0; fb < 4; ++fb) {
            const int j = wc * 64 + fb * 16 + lr;
#pragma unroll
            for (int r = 0; r < 4; ++r) {
                const int m = mbase + r;
                const size_t oidx =
                    (((size_t)b * 64 + (m >> 1)) * 128 + (m & 1) * 64 + c) * 128 + j;
                __builtin_nontemporal_store(acc[fa][fb][r], &out[oidx]);
            }
        }
    }
}

extern "C" void kernel_launch(void* const* d_in, const int* in_sizes, int n_in,
                              void* d_out, int out_size, void* d_ws, size_t ws_size,
                              hipStream_t stream) {
    const float* x    = (const float*)d_in[0];
    const float* haar = (const float*)d_in[1];
    float* out = (float*)d_out;
    unsigned short* h2t = (unsigned short*)d_ws;  // 128*256 bf16 = 64 KB

    h2t_kernel<<<dim3(256), dim3(256), 0, stream>>>(haar, h2t);
    wavelet_gemm_kernel<<<dim3(2048), dim3(256), 0, stream>>>(x, h2t, out);
}

// Round 3
// 56.244 us; speedup vs baseline: 1.8919x; 1.8919x over previous
//
#include <hip/hip_runtime.h>
#include <hip/hip_bf16.h>

// x [16,64,256,256] f32, haar [256,256] f32 -> out [16,64,128,128] f32.
// out[b,c2,i2,j2] = res[b, i2&63, 4*c2+(i2>>6), j2], res = X @ (haar@haar).
// Only x-rows i with i%4 in {0,1} and cols j<128 of res are needed.
// m = selected-row index (0..127): i = ((m>>1)<<2)|(m&1);
// store: out[((b*64+(m>>1))*128 + (m&1)*64 + c)*128 + j].

typedef __attribute__((ext_vector_type(8))) short bf16x8;
typedef __attribute__((ext_vector_type(4))) float f32x4;

static __device__ inline unsigned short bf16bits(float f) {
    __hip_bfloat16 h = __float2bfloat16(f);
    return *reinterpret_cast<unsigned short*>(&h);
}

// ------------------------------------------------------------------ kernel 1
// B_swz: H2[k][n] = sum_t haar[k][t]*haar[t][n], n in [0,128), stored bf16 in
// exact MFMA-fragment order: idx = (((fb*8+s)*64 + lg*16 + lr)<<3) + e
// where n = fb*16+lr, k = s*32 + lg*8 + e.  Total 64 KB.
__global__ void h2swz_kernel(const float* __restrict__ haar,
                             unsigned short* __restrict__ bswz) {
    __shared__ float rowk[256];
    __shared__ float part[128];
    const int k   = blockIdx.x;     // 0..255
    const int tid = threadIdx.x;    // 0..255
    const int n   = tid & 127;
    const int h   = tid >> 7;       // t-half
    rowk[tid] = haar[k * 256 + tid];
    __syncthreads();
    float acc = 0.f;
    const int t0 = h * 128;
#pragma unroll 8
    for (int t = 0; t < 128; ++t)
        acc = fmaf(rowk[t0 + t], haar[(t0 + t) * 256 + n], acc);  // coalesced in n
    if (h) part[n] = acc;
    __syncthreads();
    if (!h) {
        const int fb = n >> 4, lr = n & 15;
        const int s = k >> 5, lg = (k >> 3) & 3, e = k & 7;
        const size_t idx = ((((size_t)(fb * 8 + s)) * 64 + lg * 16 + lr) << 3) + e;
        bswz[idx] = bf16bits(acc + part[n]);
    }
}

// ------------------------------------------------------------------ kernel 2
// 2048 blocks: bid = blk*2 + mt; blk = b*64+c matrix, mt = 64-row half.
// 4 waves; wave w owns rows [mt*64 + w*16, +16), all 128 cols.
// Stage A rows dense (1 row = one 1KB coalesced load), cvt->bf16, XOR-swizzled
// LDS; wave reads only rows it wrote -> no barrier.  B loads fully dense from
// pre-swizzled L2-resident table.
__global__ void wavelet_gemm_kernel(const float* __restrict__ x,
                                    const unsigned short* __restrict__ bswz,
                                    float* __restrict__ out) {
    __shared__ __align__(16) unsigned int alds[8192];   // 32 KB: 64 rows x 512 B
    char* abase = reinterpret_cast<char*>(alds);

    const int bid  = blockIdx.x;
    const int blk  = bid >> 1;        // b*64 + c
    const int mt   = bid & 1;
    const int c    = blk & 63;
    const int b    = blk >> 6;
    const int tid  = threadIdx.x;
    const int lane = tid & 63;
    const int w    = tid >> 6;        // 0..3
    const int lr   = lane & 15;
    const int lg   = lane >> 4;

    const float* xb = x + (size_t)blk * 65536;

    // ---- stage: 16 rows/wave, one dense 1KB load per row ----
#pragma unroll
    for (int r0 = 0; r0 < 16; r0 += 8) {
        f32x4 v[8];
#pragma unroll
        for (int q = 0; q < 8; ++q) {
            const int m = mt * 64 + w * 16 + r0 + q;      // global selected row
            const int i = ((m >> 1) << 2) | (m & 1);      // x row
            v[q] = *reinterpret_cast<const f32x4*>(xb + i * 256 + lane * 4);
        }
#pragma unroll
        for (int q = 0; q < 8; ++q) {
            const int lm = w * 16 + r0 + q;               // local row 0..63
            union { unsigned short u[4]; unsigned long long d; } p;
            p.u[0] = bf16bits(v[q].x);
            p.u[1] = bf16bits(v[q].y);
            p.u[2] = bf16bits(v[q].z);
            p.u[3] = bf16bits(v[q].w);                    // lane covers k=4l..4l+3
            const int byte = (lm * 512 + lane * 8) ^ ((lm & 7) << 4);
            *reinterpret_cast<unsigned long long*>(abase + byte) = p.d;
        }
    }

    // ---- compute: 8 k-steps, 1 A-frag x 8 B-frags, 8 MFMA per step ----
    f32x4 acc[8] = {};
#pragma unroll 2
    for (int s = 0; s < 8; ++s) {
        bf16x8 bF[8];
#pragma unroll
        for (int fb = 0; fb < 8; ++fb)
            bF[fb] = *reinterpret_cast<const bf16x8*>(
                bswz + ((((size_t)(fb * 8 + s)) * 64 + lane) << 3));
        const int lm = w * 16 + lr;
        const int byte = (lm * 512 + s * 64 + lg * 16) ^ ((lm & 7) << 4);
        const bf16x8 aF = *reinterpret_cast<const bf16x8*>(abase + byte);
#pragma unroll
        for (int fb = 0; fb < 8; ++fb)
            acc[fb] = __builtin_amdgcn_mfma_f32_16x16x32_bf16(aF, bF[fb], acc[fb], 0, 0, 0);
    }

    // ---- epilogue: C/D layout col=lane&15, row=(lane>>4)*4+r ----
#pragma unroll
    for (int fb = 0; fb < 8; ++fb) {
        const int j = fb * 16 + lr;
#pragma unroll
        for (int r = 0; r < 4; ++r) {
            const int m = mt * 64 + w * 16 + lg * 4 + r;  // global selected row
            const size_t oidx =
                (((size_t)b * 64 + (m >> 1)) * 128 + (m & 1) * 64 + c) * 128 + j;
            out[oidx] = acc[fb][r];
        }
    }
}

extern "C" void kernel_launch(void* const* d_in, const int* in_sizes, int n_in,
                              void* d_out, int out_size, void* d_ws, size_t ws_size,
                              hipStream_t stream) {
    const float* x    = (const float*)d_in[0];
    const float* haar = (const float*)d_in[1];
    float* out = (float*)d_out;
    unsigned short* bswz = (unsigned short*)d_ws;   // 64 KB

    h2swz_kernel<<<dim3(256), dim3(256), 0, stream>>>(haar, bswz);
    wavelet_gemm_kernel<<<dim3(2048), dim3(256), 0, stream>>>(x, bswz, out);
}

// Round 4
// 46.268 us; speedup vs baseline: 2.2998x; 1.2156x over previous
//
#include <hip/hip_runtime.h>
#include <hip/hip_bf16.h>

// x [16,64,256,256] f32, haar [256,256] f32 -> out [16,64,128,128] f32.
// out[b,c2,i2,j2] = res[b, i2&63, 4*c2+(i2>>6), j2], res = X @ (haar@haar).
// Only x-rows i%4 in {0,1} and cols j<128 of res are needed.
// m = selected-row index (0..127): i = ((m>>1)<<2)|(m&1);
// store: out[((b*64+(m>>1))*128 + (m&1)*64 + c)*128 + j].

typedef __attribute__((ext_vector_type(8))) short bf16x8;
typedef __attribute__((ext_vector_type(4))) float f32x4;

static __device__ inline unsigned short bf16bits(float f) {
    __hip_bfloat16 h = __float2bfloat16(f);
    return *reinterpret_cast<unsigned short*>(&h);
}

// ------------------------------------------------------------------ kernel 1
// B_swz: H2[k][n] = sum_t haar[k][t]*haar[t][n], n in [0,128), bf16, stored in
// exact MFMA-fragment order: idx = (((fb*8+s)*64 + lg*16 + lr)<<3) + e
// where n = fb*16+lr, k = s*32 + lg*8 + e.  Total 64 KB.
__global__ void h2swz_kernel(const float* __restrict__ haar,
                             unsigned short* __restrict__ bswz) {
    __shared__ float rowk[256];
    __shared__ float part[128];
    const int k   = blockIdx.x;     // 0..255
    const int tid = threadIdx.x;    // 0..255
    const int n   = tid & 127;
    const int h   = tid >> 7;       // t-half
    rowk[tid] = haar[k * 256 + tid];
    __syncthreads();
    float acc = 0.f;
    const int t0 = h * 128;
#pragma unroll 8
    for (int t = 0; t < 128; ++t)
        acc = fmaf(rowk[t0 + t], haar[(t0 + t) * 256 + n], acc);  // coalesced in n
    if (h) part[n] = acc;
    __syncthreads();
    if (!h) {
        const int fb = n >> 4, lr = n & 15;
        const int s = k >> 5, lg = (k >> 3) & 3, e = k & 7;
        const size_t idx = ((((size_t)(fb * 8 + s)) * 64 + lg * 16 + lr) << 3) + e;
        bswz[idx] = bf16bits(acc + part[n]);
    }
}

// ------------------------------------------------------------------ kernel 2
// Persistent: grid 256 (1 block/CU, 128 KB LDS), 512 threads = 8 waves.
// Each block processes 4 whole matrices (blk = bid*4+it), pipelined:
//   issue item n+1's dense row loads -> compute item n entirely from LDS.
// B table lives in LDS (staged once); compute uses only lgkmcnt, so staging
// vmcnt loads float freely across the whole compute phase.
// Wave w owns sel-rows [w*16, w*16+16) x all 128 cols; reads only rows it
// wrote -> no per-item barrier.
__global__ __launch_bounds__(512, 2)
void wavelet_gemm_kernel(const float* __restrict__ x,
                         const uint4* __restrict__ bswz16,
                         float* __restrict__ out) {
    __shared__ __align__(16) char lds[131072];   // A: [0,64K) swz rows; B: [64K,128K)
    const int tid  = threadIdx.x;
    const int lane = tid & 63;
    const int w    = tid >> 6;        // 0..7
    const int lr   = lane & 15;
    const int lg   = lane >> 4;

    // ---- stage B table into LDS (64 KB, frag-order preserved) ----
    {
        uint4* bdst = reinterpret_cast<uint4*>(lds + 65536);
#pragma unroll
        for (int r = 0; r < 8; ++r)
            bdst[r * 512 + tid] = bswz16[r * 512 + tid];
    }

    // ---- prologue: issue item-0 A row loads (1 row = one dense 1KB load) ----
    f32x4 rv[16];
    const int mat0 = blockIdx.x * 4;
    {
        const float* xb = x + (size_t)mat0 * 65536;
#pragma unroll
        for (int q = 0; q < 16; ++q) {
            const int m = w * 16 + q;
            const int i = ((m >> 1) << 2) | (m & 1);
            rv[q] = reinterpret_cast<const f32x4*>(xb + i * 256)[lane];
        }
    }

    __syncthreads();   // B ready

    for (int it = 0; it < 4; ++it) {
        const int blk = mat0 + it;            // b*64 + c
        const int c = blk & 63, b = blk >> 6;

        // ---- cvt + write A rows to swizzled LDS (waits staged loads) ----
#pragma unroll
        for (int q = 0; q < 16; ++q) {
            const int lm = w * 16 + q;
            union { unsigned short u[4]; unsigned long long d; } p;
            p.u[0] = bf16bits(rv[q].x);
            p.u[1] = bf16bits(rv[q].y);
            p.u[2] = bf16bits(rv[q].z);
            p.u[3] = bf16bits(rv[q].w);       // lane covers k = 4*lane..4*lane+3
            const int byte = (lm * 512 + lane * 8) ^ ((lm & 7) << 4);
            *reinterpret_cast<unsigned long long*>(lds + byte) = p.d;
        }

        // ---- issue next item's A loads; land during compute below ----
        if (it < 3) {
            const float* xb = x + (size_t)(blk + 1) * 65536;
#pragma unroll
            for (int q = 0; q < 16; ++q) {
                const int m = w * 16 + q;
                const int i = ((m >> 1) << 2) | (m & 1);
                rv[q] = reinterpret_cast<const f32x4*>(xb + i * 256)[lane];
            }
        }

        // ---- compute: 8 k-steps, all-LDS operands, 8 MFMA each ----
        f32x4 acc[8] = {};
#pragma unroll
        for (int s = 0; s < 8; ++s) {
            const int lm = w * 16 + lr;
            const int abyte = (lm * 512 + s * 64 + lg * 16) ^ ((lm & 7) << 4);
            const bf16x8 aF = *reinterpret_cast<const bf16x8*>(lds + abyte);
#pragma unroll
            for (int fb = 0; fb < 8; ++fb) {
                const bf16x8 bF = *reinterpret_cast<const bf16x8*>(
                    lds + 65536 + (((fb * 8 + s) * 64 + lane) << 4));
                acc[fb] = __builtin_amdgcn_mfma_f32_16x16x32_bf16(aF, bF, acc[fb], 0, 0, 0);
            }
        }

        // ---- epilogue: C/D layout col=lane&15, row=(lane>>4)*4+r ----
#pragma unroll
        for (int fb = 0; fb < 8; ++fb) {
            const int j = fb * 16 + lr;
#pragma unroll
            for (int r = 0; r < 4; ++r) {
                const int m = w * 16 + lg * 4 + r;
                const size_t oidx =
                    (((size_t)b * 64 + (m >> 1)) * 128 + (m & 1) * 64 + c) * 128 + j;
                out[oidx] = acc[fb][r];
            }
        }
    }
}

extern "C" void kernel_launch(void* const* d_in, const int* in_sizes, int n_in,
                              void* d_out, int out_size, void* d_ws, size_t ws_size,
                              hipStream_t stream) {
    const float* x    = (const float*)d_in[0];
    const float* haar = (const float*)d_in[1];
    float* out = (float*)d_out;
    unsigned short* bswz = (unsigned short*)d_ws;   // 64 KB

    h2swz_kernel<<<dim3(256), dim3(256), 0, stream>>>(haar, bswz);
    wavelet_gemm_kernel<<<dim3(256), dim3(512), 0, stream>>>(
        x, reinterpret_cast<const uint4*>(bswz), out);
}

// Round 5
// 45.170 us; speedup vs baseline: 2.3557x; 1.0243x over previous
//
#include <hip/hip_runtime.h>
#include <hip/hip_bf16.h>

// x [16,64,256,256] f32, haar [256,256] f32 -> out [16,64,128,128] f32.
// out[b,c2,i2,j2] = res[b, i2&63, 4*c2+(i2>>6), j2], res = X @ (haar@haar).
// Only x-rows i%4 in {0,1} and cols j<128 of res are needed.
// m = selected-row index (0..127): i = ((m>>1)<<2)|(m&1);
// store: out[((b*64+(m>>1))*128 + (m&1)*64 + c)*128 + j].

typedef __attribute__((ext_vector_type(8))) short bf16x8;
typedef __attribute__((ext_vector_type(4))) float f32x4;

static __device__ inline unsigned short bf16bits(float f) {
    __hip_bfloat16 h = __float2bfloat16(f);
    return *reinterpret_cast<unsigned short*>(&h);
}

// ------------------------------------------------------------------ kernel 1
// B_swz: H2[k][n] = sum_t haar[k][t]*haar[t][n], n in [0,128), bf16, stored in
// MFMA-fragment order with COLUMN-PERMUTED fragment slots:
//   frag fb, lane-col lr covers output column n = (fb>>2)*64 + lr*4 + (fb&3)
//   (so each lane ends up holding 4 consecutive j -> dwordx4 stores).
// idx = (((fb*8+s)*64 + lg*16 + lr)<<3) + e, where k = s*32 + lg*8 + e.
__global__ void h2swz_kernel(const float* __restrict__ haar,
                             unsigned short* __restrict__ bswz) {
    __shared__ float rowk[256];
    __shared__ float part[128];
    const int k   = blockIdx.x;     // 0..255
    const int tid = threadIdx.x;    // 0..255
    const int n   = tid & 127;
    const int h   = tid >> 7;       // t-half
    rowk[tid] = haar[k * 256 + tid];
    __syncthreads();
    float a0 = 0.f, a1 = 0.f, a2 = 0.f, a3 = 0.f;
    const int t0 = h * 128;
#pragma unroll 8
    for (int t = 0; t < 128; t += 4) {
        a0 = fmaf(rowk[t0 + t + 0], haar[(t0 + t + 0) * 256 + n], a0);
        a1 = fmaf(rowk[t0 + t + 1], haar[(t0 + t + 1) * 256 + n], a1);
        a2 = fmaf(rowk[t0 + t + 2], haar[(t0 + t + 2) * 256 + n], a2);
        a3 = fmaf(rowk[t0 + t + 3], haar[(t0 + t + 3) * 256 + n], a3);
    }
    const float acc = (a0 + a1) + (a2 + a3);
    if (h) part[n] = acc;
    __syncthreads();
    if (!h) {
        const int hi = n >> 6, lr = (n & 63) >> 2, q = n & 3;
        const int fb = hi * 4 + q;
        const int s = k >> 5, lg = (k >> 3) & 3, e = k & 7;
        const size_t idx = ((((size_t)(fb * 8 + s)) * 64 + lg * 16 + lr) << 3) + e;
        bswz[idx] = bf16bits(acc + part[n]);
    }
}

// ------------------------------------------------------------------ kernel 2
// Persistent: grid 256 (1 block/CU, 128 KB LDS), 512 threads = 8 waves.
// Each block processes 4 matrices (blk = bid*4+it), depth-2 register pipeline:
// loads for items it+1 and it+2 stay in flight while item it computes from
// LDS only (compute phase has zero vmcnt dependence).
// Wave w owns sel-rows [w*16, w*16+16) x all 128 cols; reads only LDS rows it
// wrote itself -> no per-item barrier.
__global__ __launch_bounds__(512, 2)
void wavelet_gemm_kernel(const float* __restrict__ x,
                         const uint4* __restrict__ bswz16,
                         float* __restrict__ out) {
    __shared__ __align__(16) char lds[131072];   // A swz rows [0,64K); B [64K,128K)
    const int tid  = threadIdx.x;
    const int lane = tid & 63;
    const int w    = tid >> 6;        // 0..7
    const int lr   = lane & 15;
    const int lg   = lane >> 4;

    // ---- stage B table into LDS (64 KB, frag-order preserved) ----
    {
        uint4* bdst = reinterpret_cast<uint4*>(lds + 65536);
#pragma unroll
        for (int r = 0; r < 8; ++r)
            bdst[r * 512 + tid] = bswz16[r * 512 + tid];
    }

    const int mat0 = blockIdx.x * 4;

    // Row addressing: wave w, slot q -> selected row m = w*16+q, x row i.
    // ---- prologue: issue item-0 and item-1 A row loads (dense 1KB each) ----
    f32x4 rvA[16], rvB[16];
#pragma unroll
    for (int q = 0; q < 16; ++q) {
        const int m = w * 16 + q;
        const int i = ((m >> 1) << 2) | (m & 1);
        rvA[q] = reinterpret_cast<const f32x4*>(x + (size_t)mat0 * 65536 + i * 256)[lane];
    }
#pragma unroll
    for (int q = 0; q < 16; ++q) {
        const int m = w * 16 + q;
        const int i = ((m >> 1) << 2) | (m & 1);
        rvB[q] = reinterpret_cast<const f32x4*>(x + (size_t)(mat0 + 1) * 65536 + i * 256)[lane];
    }

    __syncthreads();   // B table ready

#pragma unroll
    for (int it = 0; it < 4; ++it) {
        const int blk = mat0 + it;            // b*64 + c
        const int c = blk & 63, b = blk >> 6;
        f32x4* cur = (it & 1) ? rvB : rvA;    // statically resolved (unrolled)

        // ---- cvt + write A rows to swizzled LDS (drains this item's loads) ----
#pragma unroll
        for (int q = 0; q < 16; ++q) {
            const int lm = w * 16 + q;
            union { unsigned short u[4]; unsigned long long d; } p;
            p.u[0] = bf16bits(cur[q].x);
            p.u[1] = bf16bits(cur[q].y);
            p.u[2] = bf16bits(cur[q].z);
            p.u[3] = bf16bits(cur[q].w);      // lane covers k = 4*lane..4*lane+3
            const int byte = (lm * 512 + lane * 8) ^ ((lm & 7) << 4);
            *reinterpret_cast<unsigned long long*>(lds + byte) = p.d;
        }

        // ---- refill the just-consumed buffer with item it+2 ----
        if (it < 2) {
            const float* xb = x + (size_t)(blk + 2) * 65536;
#pragma unroll
            for (int q = 0; q < 16; ++q) {
                const int m = w * 16 + q;
                const int i = ((m >> 1) << 2) | (m & 1);
                cur[q] = reinterpret_cast<const f32x4*>(xb + i * 256)[lane];
            }
        }

        // ---- compute: 8 k-steps, all-LDS operands, 8 MFMA each ----
        f32x4 acc[8] = {};
#pragma unroll
        for (int s = 0; s < 8; ++s) {
            const int lm = w * 16 + lr;
            const int abyte = (lm * 512 + s * 64 + lg * 16) ^ ((lm & 7) << 4);
            const bf16x8 aF = *reinterpret_cast<const bf16x8*>(lds + abyte);
#pragma unroll
            for (int fb = 0; fb < 8; ++fb) {
                const bf16x8 bF = *reinterpret_cast<const bf16x8*>(
                    lds + 65536 + (((fb * 8 + s) * 64 + lane) << 4));
                acc[fb] = __builtin_amdgcn_mfma_f32_16x16x32_bf16(aF, bF, acc[fb], 0, 0, 0);
            }
        }

        // ---- epilogue: C/D row=(lane>>4)*4+r, frag col lr -> j=(hi)*64+lr*4+q.
        // Lane lr holds j = hi*64 + lr*4 + (0..3) in acc[hi*4 + 0..3][r]:
        // two dense f32x4 stores per r (256B contiguous per 16-lane group).
#pragma unroll
        for (int r = 0; r < 4; ++r) {
            const int m = w * 16 + lg * 4 + r;
            float* rowp = out + (((size_t)b * 64 + (m >> 1)) * 128 + (m & 1) * 64 + c) * 128;
            f32x4 v0 = {acc[0][r], acc[1][r], acc[2][r], acc[3][r]};
            f32x4 v1 = {acc[4][r], acc[5][r], acc[6][r], acc[7][r]};
            *reinterpret_cast<f32x4*>(rowp + lr * 4)      = v0;
            *reinterpret_cast<f32x4*>(rowp + 64 + lr * 4) = v1;
        }
    }
}

extern "C" void kernel_launch(void* const* d_in, const int* in_sizes, int n_in,
                              void* d_out, int out_size, void* d_ws, size_t ws_size,
                              hipStream_t stream) {
    const float* x    = (const float*)d_in[0];
    const float* haar = (const float*)d_in[1];
    float* out = (float*)d_out;
    unsigned short* bswz = (unsigned short*)d_ws;   // 64 KB

    h2swz_kernel<<<dim3(256), dim3(256), 0, stream>>>(haar, bswz);
    wavelet_gemm_kernel<<<dim3(256), dim3(512), 0, stream>>>(
        x, reinterpret_cast<const uint4*>(bswz), out);
}